// Round 1
// baseline (156.719 us; speedup 1.0000x reference)
//
#include <hip/hip_runtime.h>

typedef __attribute__((ext_vector_type(8))) short short8_t;
typedef __attribute__((ext_vector_type(4))) float f32x4;

#define AS1 __attribute__((address_space(1)))
#define AS3 __attribute__((address_space(3)))

static_assert(sizeof(short8_t) == 16, "short8_t must be 16B");

__device__ __forceinline__ short f2bf(float f) {
  union { float f; unsigned u; } v; v.f = f;
  unsigned r = (v.u + 0x7FFFu + ((v.u >> 16) & 1u)) >> 16;
  return (short)r;
}
__device__ __forceinline__ float bf2f(short s) {
  union { unsigned u; float f; } v; v.u = ((unsigned)(unsigned short)s) << 16;
  return v.f;
}

// ---------------- CSR build ----------------
__global__ __launch_bounds__(256) void count_deg(const int* __restrict__ ei,
                                                 int* __restrict__ deg, int E) {
  int e = blockIdx.x * 256 + threadIdx.x;
  if (e < E) atomicAdd(&deg[ei[e]], 1);
}

// N=4096 fixed: 1024 threads, each owns 4 elements; Hillis-Steele on partials.
__global__ __launch_bounds__(1024) void scan_deg(const int* __restrict__ deg,
                                                 int* __restrict__ rp,
                                                 float* __restrict__ dis) {
  __shared__ int part[1024];
  const int t = threadIdx.x;
  int4 v = ((const int4*)deg)[t];
  const int s = v.x + v.y + v.z + v.w;
  part[t] = s;
  __syncthreads();
  for (int off = 1; off < 1024; off <<= 1) {
    int mine = part[t];
    int add = (t >= off) ? part[t - off] : 0;
    __syncthreads();
    part[t] = mine + add;
    __syncthreads();
  }
  const int excl = part[t] - s;
  const int b4 = t * 4;
  rp[b4 + 0] = excl;
  rp[b4 + 1] = excl + v.x;
  rp[b4 + 2] = excl + v.x + v.y;
  rp[b4 + 3] = excl + v.x + v.y + v.z;
  if (t == 1023) rp[4096] = part[1023];
  dis[b4 + 0] = rsqrtf((float)(v.x + 1));   // +1 self-loop; deg >= 1 always
  dis[b4 + 1] = rsqrtf((float)(v.y + 1));
  dis[b4 + 2] = rsqrtf((float)(v.z + 1));
  dis[b4 + 3] = rsqrtf((float)(v.w + 1));
}

__global__ __launch_bounds__(256) void fill_csr(const int* __restrict__ ei,
                                                const int* __restrict__ rp,
                                                int* __restrict__ fill,
                                                int* __restrict__ cols, int E) {
  int e = blockIdx.x * 256 + threadIdx.x;
  if (e < E) {
    int r = ei[e];
    int c = ei[E + e];
    int p = atomicAdd(&fill[r], 1);
    cols[rp[r] + p] = c;
  }
}

// ---------------- x [B][C][N] -> xs [B][N][C], pre-scaled by dis[n] ----------
__global__ __launch_bounds__(256) void xpose_scale(const float* __restrict__ x,
                                                   const float* __restrict__ dis,
                                                   float* __restrict__ xs) {
  __shared__ float tile[32][33];
  const int b = blockIdx.z;
  const int n0 = blockIdx.x * 32;
  const int c0 = blockIdx.y * 32;
  const int tx = threadIdx.x, ty = threadIdx.y;  // (32,8)
  const float* xb = x + (long)b * 256 * 4096;
#pragma unroll
  for (int i = 0; i < 32; i += 8)
    tile[ty + i][tx] = xb[(long)(c0 + ty + i) * 4096 + n0 + tx];
  __syncthreads();
  float* xsb = xs + (long)b * 4096 * 256;
#pragma unroll
  for (int i = 0; i < 32; i += 8) {
    const int n = n0 + ty + i;
    xsb[(long)n * 256 + c0 + tx] = tile[tx][ty + i] * dis[n];
  }
}

// -------- message passing: h0[b,m,:] = bf16(dis[m]*(xs[b,m,:] + sum_nbr xs)) --
__global__ __launch_bounds__(64) void gather_mp(const float* __restrict__ xs,
                                                const float* __restrict__ dis,
                                                const int* __restrict__ rp,
                                                const int* __restrict__ cols,
                                                short* __restrict__ h0) {
  const int bm = blockIdx.x;         // b*4096 + m
  const int m = bm & 4095;
  const int t = threadIdx.x;         // 64 lanes * float4 = 256 channels
  const float4* xsb = (const float4*)(xs + ((long)(bm >> 12)) * 4096 * 256);
  float4 a = xsb[(long)m * 64 + t];  // self-loop (already scaled by dis[m])
  const int s = rp[m], e = rp[m + 1];
  for (int j = s; j < e; ++j) {
    const int n = cols[j];
    float4 v = xsb[(long)n * 64 + t];
    a.x += v.x; a.y += v.y; a.z += v.z; a.w += v.w;
  }
  const float d = dis[m];
  short4 o;
  o.x = f2bf(a.x * d); o.y = f2bf(a.y * d); o.z = f2bf(a.z * d); o.w = f2bf(a.w * d);
  ((short4*)(h0 + (long)bm * 256))[t] = o;
}

// ---------------- W [K][N] fp32 -> Wt [N][K] bf16 ----------------
__global__ __launch_bounds__(256) void wt_cast(const float* __restrict__ Wf,
                                               short* __restrict__ Wt, int K, int N) {
  __shared__ float tile[32][33];
  const int k0 = blockIdx.x * 32;
  const int n0 = blockIdx.y * 32;
  const int tx = threadIdx.x, ty = threadIdx.y;
#pragma unroll
  for (int i = 0; i < 32; i += 8)
    tile[ty + i][tx] = Wf[(long)(k0 + ty + i) * N + n0 + tx];
  __syncthreads();
#pragma unroll
  for (int i = 0; i < 32; i += 8)
    Wt[(long)(n0 + ty + i) * K + k0 + tx] = f2bf(tile[tx][ty + i]);
}

// ---------------- GEMM: A[M][K] bf16, Bt[N][K] bf16 -> out bf16 (bias,+relu) --
// m97 structure: 128x128 tile, BK=32, 4 waves (2x2), 16x16x32 MFMA,
// global_load_lds width 16, linear LDS.
template <bool RELU>
__global__ __launch_bounds__(256, 2) void gemm_bf16(const short* __restrict__ A,
                                                    const short* __restrict__ Bt,
                                                    const float* __restrict__ bias,
                                                    short* __restrict__ out,
                                                    int M, int N, int K) {
  __shared__ __align__(16) short As[128 * 32];
  __shared__ __align__(16) short Bs[128 * 32];
  const int tid = threadIdx.x;
  const int lane = tid & 63;
  const int wave = tid >> 6;        // 0..3
  const int wm = wave >> 1;         // 2x2 wave grid, each wave 64x64
  const int wn = wave & 1;
  const int m0 = blockIdx.x * 128;
  const int n0 = blockIdx.y * 128;

  f32x4 acc[4][4] = {};

  // staging: wave w loads tile rows [w*32, w*32+32); lane -> row w*32 + (lane>>2),
  // byte col (lane&3)*16. One wave-instr = 16 rows = 1KB contiguous LDS.
  const int srow = wave * 32 + (lane >> 2);
  const int scol = (lane & 3) * 8;
  const short* ag = A + (long)(m0 + srow) * K + scol;
  const short* bg = Bt + (long)(n0 + srow) * K + scol;
  short* asl = &As[(wave * 32) * 32];
  short* bsl = &Bs[(wave * 32) * 32];

  const int fr = lane & 15;
  const int kc = (lane >> 4) * 8;

  for (int k0 = 0; k0 < K; k0 += 32) {
    __syncthreads();
    __builtin_amdgcn_global_load_lds((const AS1 void*)(ag + k0), (AS3 void*)asl, 16, 0, 0);
    __builtin_amdgcn_global_load_lds((const AS1 void*)(ag + k0 + 16 * K),
                                     (AS3 void*)(asl + 16 * 32), 16, 0, 0);
    __builtin_amdgcn_global_load_lds((const AS1 void*)(bg + k0), (AS3 void*)bsl, 16, 0, 0);
    __builtin_amdgcn_global_load_lds((const AS1 void*)(bg + k0 + 16 * K),
                                     (AS3 void*)(bsl + 16 * 32), 16, 0, 0);
    __syncthreads();

    short8_t af[4], bf[4];
#pragma unroll
    for (int i = 0; i < 4; ++i)
      af[i] = *(const short8_t*)&As[(wm * 64 + i * 16 + fr) * 32 + kc];
#pragma unroll
    for (int i = 0; i < 4; ++i)
      bf[i] = *(const short8_t*)&Bs[(wn * 64 + i * 16 + fr) * 32 + kc];
#pragma unroll
    for (int mi = 0; mi < 4; ++mi)
#pragma unroll
      for (int ni = 0; ni < 4; ++ni)
        acc[mi][ni] = __builtin_amdgcn_mfma_f32_16x16x32_bf16(af[mi], bf[ni],
                                                              acc[mi][ni], 0, 0, 0);
  }

  // C/D layout (m91-verified): col = lane&15, row = (lane>>4)*4 + reg
  const int rq = (lane >> 4) * 4;
#pragma unroll
  for (int mi = 0; mi < 4; ++mi) {
#pragma unroll
    for (int ni = 0; ni < 4; ++ni) {
      const int col = n0 + wn * 64 + ni * 16 + fr;
      const float bv = bias[col];
#pragma unroll
      for (int r = 0; r < 4; ++r) {
        const int row = m0 + wm * 64 + mi * 16 + rq + r;
        float v = acc[mi][ni][r] + bv;
        if (RELU) v = fmaxf(v, 0.0f);
        out[(long)row * N + col] = f2bf(v);
      }
    }
  }
}

// ---------------- LayerNorm over rows of length L (bf16 in) ----------------
template <int L, bool OUTF32>
__global__ __launch_bounds__(256) void ln_rows(const short* __restrict__ in,
                                               const float* __restrict__ g,
                                               const float* __restrict__ be,
                                               void* __restrict__ outv) {
  const int lane = threadIdx.x & 63;
  const int w = threadIdx.x >> 6;
  const long row = (long)blockIdx.x * 4 + w;
  const short* p = in + row * L;
  constexpr int V = L / 256;  // short4-chunks per lane
  float x[V * 4];
  float sum = 0.f, sq = 0.f;
#pragma unroll
  for (int i = 0; i < V; ++i) {
    short4 s = ((const short4*)p)[lane + i * 64];
    float a = bf2f(s.x), b = bf2f(s.y), c = bf2f(s.z), d = bf2f(s.w);
    x[i * 4 + 0] = a; x[i * 4 + 1] = b; x[i * 4 + 2] = c; x[i * 4 + 3] = d;
    sum += a + b + c + d;
    sq += a * a + b * b + c * c + d * d;
  }
#pragma unroll
  for (int off = 32; off > 0; off >>= 1) {
    sum += __shfl_xor(sum, off);
    sq += __shfl_xor(sq, off);
  }
  const float mu = sum * (1.0f / L);
  float var = sq * (1.0f / L) - mu * mu;
  var = fmaxf(var, 0.0f);
  const float inv = rsqrtf(var + 1e-5f);
#pragma unroll
  for (int i = 0; i < V; ++i) {
    float4 gv = ((const float4*)g)[lane + i * 64];
    float4 bv = ((const float4*)be)[lane + i * 64];
    float y0 = (x[i * 4 + 0] - mu) * inv * gv.x + bv.x;
    float y1 = (x[i * 4 + 1] - mu) * inv * gv.y + bv.y;
    float y2 = (x[i * 4 + 2] - mu) * inv * gv.z + bv.z;
    float y3 = (x[i * 4 + 3] - mu) * inv * gv.w + bv.w;
    if constexpr (OUTF32) {
      float4 o; o.x = y0; o.y = y1; o.z = y2; o.w = y3;
      ((float4*)((float*)outv + row * L))[lane + i * 64] = o;
    } else {
      short4 o; o.x = f2bf(y0); o.y = f2bf(y1); o.z = f2bf(y2); o.w = f2bf(y3);
      ((short4*)((short*)outv + row * L))[lane + i * 64] = o;
    }
  }
}

// ---------------- y [B][N][C] fp32 -> out [B][C][N] fp32 ----------------
__global__ __launch_bounds__(256) void xpose_out(const float* __restrict__ y,
                                                 float* __restrict__ out) {
  __shared__ float tile[32][33];
  const int b = blockIdx.z;
  const int n0 = blockIdx.x * 32;
  const int c0 = blockIdx.y * 32;
  const int tx = threadIdx.x, ty = threadIdx.y;
#pragma unroll
  for (int i = 0; i < 32; i += 8)
    tile[ty + i][tx] = y[(long)b * 4096 * 256 + (long)(n0 + ty + i) * 256 + c0 + tx];
  __syncthreads();
#pragma unroll
  for (int i = 0; i < 32; i += 8)
    out[(long)b * 256 * 4096 + (long)(c0 + ty + i) * 4096 + n0 + tx] = tile[tx][ty + i];
}

extern "C" void kernel_launch(void* const* d_in, const int* in_sizes, int n_in,
                              void* d_out, int out_size, void* d_ws, size_t ws_size,
                              hipStream_t stream) {
  (void)n_in; (void)out_size; (void)ws_size;
  const float* x   = (const float*)d_in[0];
  const int*   ei  = (const int*)d_in[1];
  const float* W1  = (const float*)d_in[2];
  const float* b1  = (const float*)d_in[3];
  const float* g1  = (const float*)d_in[4];
  const float* be1 = (const float*)d_in[5];
  const float* W2  = (const float*)d_in[6];
  const float* b2  = (const float*)d_in[7];
  const float* g2  = (const float*)d_in[8];
  const float* be2 = (const float*)d_in[9];
  const float* W3  = (const float*)d_in[10];
  const float* b3  = (const float*)d_in[11];
  const float* go  = (const float*)d_in[12];
  const float* bo  = (const float*)d_in[13];
  float* out = (float*)d_out;
  const int E = in_sizes[1] / 2;  // 65536

  // workspace layout (needs ~84MB)
  char* w = (char*)d_ws;
  int*   deg  = (int*)(w + 0);            // 16KB
  int*   fil  = (int*)(w + (16 << 10));   // 16KB
  int*   rp   = (int*)(w + (32 << 10));   // 16.4KB
  float* dis  = (float*)(w + (64 << 10)); // 16KB
  int*   cols = (int*)(w + (80 << 10));   // 256KB
  short* w1t  = (short*)(w + (512 << 10));
  short* w2t  = (short*)(w + (1 << 20));
  short* w3t  = (short*)(w + (2 << 20));
  char* RA = w + (4ull << 20);    // 32MB region
  char* RB = w + (36ull << 20);   // 16MB region
  char* RC = w + (52ull << 20);   // 32MB region
  float* xs = (float*)RA;   // [B][N][C] fp32, 16MB
  short* h0 = (short*)RB;   // [M][256] bf16, 8MB
  short* t1 = (short*)RC;   // [M][1024] bf16, 32MB
  short* h1 = (short*)RA;   // [M][1024] bf16, 32MB
  short* t2 = (short*)RB;   // [M][512] bf16, 16MB
  short* h2 = (short*)RC;   // [M][512] bf16, 16MB
  short* t3 = (short*)RB;   // [M][256] bf16, 8MB
  float* y3 = (float*)RA;   // [M][256] fp32, 16MB

  hipMemsetAsync(d_ws, 0, 32 << 10, stream);  // deg + fill
  count_deg<<<(E + 255) / 256, 256, 0, stream>>>(ei, deg, E);
  scan_deg<<<1, 1024, 0, stream>>>(deg, rp, dis);
  fill_csr<<<(E + 255) / 256, 256, 0, stream>>>(ei, rp, fil, cols, E);
  wt_cast<<<dim3(8, 32), dim3(32, 8), 0, stream>>>(W1, w1t, 256, 1024);
  wt_cast<<<dim3(32, 16), dim3(32, 8), 0, stream>>>(W2, w2t, 1024, 512);
  wt_cast<<<dim3(16, 8), dim3(32, 8), 0, stream>>>(W3, w3t, 512, 256);
  xpose_scale<<<dim3(128, 8, 4), dim3(32, 8), 0, stream>>>(x, dis, xs);
  gather_mp<<<16384, 64, 0, stream>>>(xs, dis, rp, cols, h0);
  gemm_bf16<true><<<dim3(128, 8), 256, 0, stream>>>(h0, w1t, b1, t1, 16384, 1024, 256);
  ln_rows<1024, false><<<4096, 256, 0, stream>>>(t1, g1, be1, (void*)h1);
  gemm_bf16<true><<<dim3(128, 4), 256, 0, stream>>>(h1, w2t, b2, t2, 16384, 512, 1024);
  ln_rows<512, false><<<4096, 256, 0, stream>>>(t2, g2, be2, (void*)h2);
  gemm_bf16<false><<<dim3(128, 2), 256, 0, stream>>>(h2, w3t, b3, t3, 16384, 256, 512);
  ln_rows<256, true><<<4096, 256, 0, stream>>>(t3, go, bo, (void*)y3);
  xpose_out<<<dim3(128, 8, 4), dim3(32, 8), 0, stream>>>(y3, out);
}

// Round 2
// 147.735 us; speedup vs baseline: 1.0608x; 1.0608x over previous
//
#include <hip/hip_runtime.h>

typedef __attribute__((ext_vector_type(8))) short short8_t;
typedef __attribute__((ext_vector_type(4))) float f32x4;

#define AS1 __attribute__((address_space(1)))
#define AS3 __attribute__((address_space(3)))

static_assert(sizeof(short8_t) == 16, "short8_t must be 16B");

__device__ __forceinline__ short f2bf(float f) {
  union { float f; unsigned u; } v; v.f = f;
  unsigned r = (v.u + 0x7FFFu + ((v.u >> 16) & 1u)) >> 16;
  return (short)r;
}
__device__ __forceinline__ float bf2f(short s) {
  union { unsigned u; float f; } v; v.u = ((unsigned)(unsigned short)s) << 16;
  return v.f;
}

// ---------------- CSR: degree count ----------------
__global__ __launch_bounds__(256) void count_deg(const int* __restrict__ ei,
                                                 int* __restrict__ deg, int E) {
  int e = blockIdx.x * 256 + threadIdx.x;
  if (e < E) atomicAdd(&deg[ei[e]], 1);
}

// N=4096 fixed: 1024 threads, 4 elems each; Hillis-Steele on partials.
__global__ __launch_bounds__(1024) void scan_deg(const int* __restrict__ deg,
                                                 int* __restrict__ rp,
                                                 float* __restrict__ dis) {
  __shared__ int part[1024];
  const int t = threadIdx.x;
  int4 v = ((const int4*)deg)[t];
  const int s = v.x + v.y + v.z + v.w;
  part[t] = s;
  __syncthreads();
  for (int off = 1; off < 1024; off <<= 1) {
    int mine = part[t];
    int add = (t >= off) ? part[t - off] : 0;
    __syncthreads();
    part[t] = mine + add;
    __syncthreads();
  }
  const int excl = part[t] - s;
  const int b4 = t * 4;
  rp[b4 + 0] = excl;
  rp[b4 + 1] = excl + v.x;
  rp[b4 + 2] = excl + v.x + v.y;
  rp[b4 + 3] = excl + v.x + v.y + v.z;
  if (t == 1023) rp[4096] = part[1023];
  dis[b4 + 0] = rsqrtf((float)(v.x + 1));
  dis[b4 + 1] = rsqrtf((float)(v.y + 1));
  dis[b4 + 2] = rsqrtf((float)(v.z + 1));
  dis[b4 + 3] = rsqrtf((float)(v.w + 1));
}

// ---------------- merged prep: CSR fill | x-transpose->xs bf16 | weight casts --
// block (32,8). bid<256: fill_csr. bid<4352: xpose+scale. else: wt cast+colsums.
__global__ __launch_bounds__(256) void prep(
    const int* __restrict__ ei, const int* __restrict__ rp, int* __restrict__ fil,
    int* __restrict__ cols, int E,
    const float* __restrict__ x, const float* __restrict__ dis, short* __restrict__ xs,
    const float* __restrict__ W1, const float* __restrict__ W2, const float* __restrict__ W3,
    const float* __restrict__ g1, const float* __restrict__ be1,
    const float* __restrict__ g2, const float* __restrict__ be2,
    short* __restrict__ w1t, short* __restrict__ w2t, short* __restrict__ w3t,
    float* __restrict__ cs2, float* __restrict__ ct2,
    float* __restrict__ cs3, float* __restrict__ ct3) {
  __shared__ float tile[32][33];
  const int tx = threadIdx.x, ty = threadIdx.y;
  const int bid = blockIdx.x;
  if (bid < 256) {  // CSR fill
    const int e = bid * 256 + ty * 32 + tx;
    if (e < E) {
      const int r = ei[e], c = ei[E + e];
      const int p = atomicAdd(&fil[r], 1);
      cols[rp[r] + p] = c;
    }
    return;
  }
  if (bid < 256 + 4096) {  // x [B][C][N] -> xs [N][B*C] bf16, scaled by dis[n]
    const int id = bid - 256;
    const int b = id >> 10;
    const int n0 = ((id & 1023) >> 3) * 32;
    const int c0 = (id & 7) * 32;
    const float* xb = x + (long)b * (256 * 4096);
#pragma unroll
    for (int i = 0; i < 32; i += 8)
      tile[ty + i][tx] = xb[(long)(c0 + ty + i) * 4096 + n0 + tx];
    __syncthreads();
#pragma unroll
    for (int i = 0; i < 32; i += 8) {
      const int n = n0 + ty + i;
      xs[(long)n * 1024 + b * 256 + c0 + tx] = f2bf(tile[tx][ty + i] * dis[n]);
    }
    return;
  }
  // weight cast: Wt[n][k] = bf16(g_prev[k]*W[k][n]); cs[n]=sum_k g*W; ct[n]=sum_k be*W
  int id = bid - 4352;
  const float *Wf, *g = nullptr, *be = nullptr;
  float *cs = nullptr, *ctp = nullptr;
  short* Wt;
  int K, N, k0, n0;
  if (id < 256)      { Wf = W1; Wt = w1t; K = 256;  N = 1024; k0 = (id & 7) * 32;  n0 = (id >> 3) * 32; }
  else if (id < 768) { id -= 256; Wf = W2; Wt = w2t; K = 1024; N = 512; k0 = (id & 31) * 32; n0 = (id >> 5) * 32;
                       g = g1; be = be1; cs = cs2; ctp = ct2; }
  else               { id -= 768; Wf = W3; Wt = w3t; K = 512;  N = 256; k0 = (id & 15) * 32; n0 = (id >> 4) * 32;
                       g = g2; be = be2; cs = cs3; ctp = ct3; }
  float csp = 0.f, ctv = 0.f;
#pragma unroll
  for (int i = 0; i < 32; i += 8) {
    const int k = k0 + ty + i;
    const float wv = Wf[(long)k * N + n0 + tx];
    const float gk = g ? g[k] : 1.0f;
    tile[ty + i][tx] = gk * wv;
    csp += gk * wv;
    if (be) ctv += be[k] * wv;
  }
  __syncthreads();
#pragma unroll
  for (int i = 0; i < 32; i += 8)
    Wt[(long)(n0 + ty + i) * K + k0 + tx] = f2bf(tile[tx][ty + i]);
  if (cs) {
    atomicAdd(&cs[n0 + tx], csp);
    atomicAdd(&ctp[n0 + tx], ctv);
  }
}

// -------- gather: one block per node, all 4 batches; xs[n][1024] bf16 --------
__global__ __launch_bounds__(256) void gather_mp(const short* __restrict__ xs,
                                                 const float* __restrict__ dis,
                                                 const int* __restrict__ rp,
                                                 const int* __restrict__ cols,
                                                 short* __restrict__ h0) {
  __shared__ int sc[256];
  const int m = blockIdx.x;
  const int t = threadIdx.x;
  short4 v0 = ((const short4*)(xs + (long)m * 1024))[t];
  float a0 = bf2f(v0.x), a1 = bf2f(v0.y), a2 = bf2f(v0.z), a3 = bf2f(v0.w);
  const int s = rp[m], e = rp[m + 1];
  for (int base = s; base < e; base += 256) {
    const int cnt = min(256, e - base);
    __syncthreads();
    if (t < cnt) sc[t] = cols[base + t];
    __syncthreads();
    for (int j = 0; j < cnt; ++j) {
      const int n = sc[j];
      short4 v = ((const short4*)(xs + (long)n * 1024))[t];
      a0 += bf2f(v.x); a1 += bf2f(v.y); a2 += bf2f(v.z); a3 += bf2f(v.w);
    }
  }
  const float d = dis[m];
  short4 o;
  o.x = f2bf(a0 * d); o.y = f2bf(a1 * d); o.z = f2bf(a2 * d); o.w = f2bf(a3 * d);
  const int b = t >> 6, c4 = t & 63;
  ((short4*)(h0 + (((long)b << 12) + m) * 256))[c4] = o;
}

// ---------------- GEMM with LN-in correction + stats-out epilogue ------------
// A[M][K] bf16 (raw prev-layer output), Bt[N][K] bf16 (g-prescaled weights).
// LNIN: v = r_m*acc - r_m*mu_m*cs[n] + ct[n] + bias[n]   (stats from statsIn, L=K)
// else: v = acc + bias[n].  Optional relu. Writes bf16; accumulates row
// sum/sumsq of fp32 v into statsOut via 16-lane shfl reduce + atomics.
// 128x128 tile, BK=32, 2x2 waves, 2-phase double-buffered global_load_lds.
template <bool LNIN, bool RELU>
__global__ __launch_bounds__(256, 2) void gemm_ln(
    const short* __restrict__ A, const short* __restrict__ Bt,
    const float* __restrict__ bias, const float* __restrict__ cs,
    const float* __restrict__ ct, const float* __restrict__ statsIn,
    float* __restrict__ statsOut, short* __restrict__ out,
    int M, int N, int K) {
  __shared__ __align__(16) short As[2][128 * 32];
  __shared__ __align__(16) short Bs[2][128 * 32];
  const int tid = threadIdx.x;
  const int lane = tid & 63;
  const int wave = tid >> 6;
  const int wm = wave >> 1, wn = wave & 1;
  const int m0 = blockIdx.x * 128, n0 = blockIdx.y * 128;

  f32x4 acc[4][4] = {};

  const int srow = wave * 32 + (lane >> 2);
  const int scol = (lane & 3) * 8;
  const short* ag = A + (long)(m0 + srow) * K + scol;
  const short* bg = Bt + (long)(n0 + srow) * K + scol;
  const int ldst = (wave * 32) * 32;
  const int fr = lane & 15;
  const int kc = (lane >> 4) * 8;
  const int NT = K >> 5;

#define STAGE(T, BUF)                                                                        \
  do {                                                                                       \
    const short* a_ = ag + (T) * 32;                                                         \
    const short* b_ = bg + (T) * 32;                                                         \
    __builtin_amdgcn_global_load_lds((const AS1 void*)a_, (AS3 void*)(&As[BUF][ldst]), 16, 0, 0); \
    __builtin_amdgcn_global_load_lds((const AS1 void*)(a_ + 16 * K), (AS3 void*)(&As[BUF][ldst + 512]), 16, 0, 0); \
    __builtin_amdgcn_global_load_lds((const AS1 void*)b_, (AS3 void*)(&Bs[BUF][ldst]), 16, 0, 0); \
    __builtin_amdgcn_global_load_lds((const AS1 void*)(b_ + 16 * K), (AS3 void*)(&Bs[BUF][ldst + 512]), 16, 0, 0); \
  } while (0)

  STAGE(0, 0);
  __syncthreads();
  int cur = 0;
  for (int t = 0; t < NT; ++t) {
    if (t + 1 < NT) STAGE(t + 1, cur ^ 1);  // prefetch overlaps this tile's MFMA
    short8_t af[4], bf[4];
#pragma unroll
    for (int i = 0; i < 4; ++i)
      af[i] = *(const short8_t*)&As[cur][(wm * 64 + i * 16 + fr) * 32 + kc];
#pragma unroll
    for (int i = 0; i < 4; ++i)
      bf[i] = *(const short8_t*)&Bs[cur][(wn * 64 + i * 16 + fr) * 32 + kc];
#pragma unroll
    for (int mi = 0; mi < 4; ++mi)
#pragma unroll
      for (int ni = 0; ni < 4; ++ni)
        acc[mi][ni] = __builtin_amdgcn_mfma_f32_16x16x32_bf16(af[mi], bf[ni],
                                                              acc[mi][ni], 0, 0, 0);
    __syncthreads();  // implicit vmcnt(0): prefetch landed; buffer swap safe
    cur ^= 1;
  }
#undef STAGE

  // epilogue: C/D layout col=lane&15, row=(lane>>4)*4+reg (m91-verified)
  const int rq = (lane >> 4) * 4;
  const float invK = 1.0f / (float)K;
  float bv[4], csv[4], ctv[4];
#pragma unroll
  for (int ni = 0; ni < 4; ++ni) {
    const int col = n0 + wn * 64 + ni * 16 + fr;
    bv[ni] = bias[col];
    if (LNIN) { csv[ni] = cs[col]; ctv[ni] = ct[col]; }
  }
#pragma unroll
  for (int mi = 0; mi < 4; ++mi) {
    float r1[4], rmu[4];
    if (LNIN) {
#pragma unroll
      for (int r = 0; r < 4; ++r) {
        const int row = m0 + wm * 64 + mi * 16 + rq + r;
        const float s = statsIn[row * 2];
        const float q = statsIn[row * 2 + 1];
        const float mu = s * invK;
        const float var = fmaxf(q * invK - mu * mu, 0.0f);
        const float rr = rsqrtf(var + 1e-5f);
        r1[r] = rr; rmu[r] = rr * mu;
      }
    }
    float sv[4] = {0, 0, 0, 0}, qv[4] = {0, 0, 0, 0};
#pragma unroll
    for (int ni = 0; ni < 4; ++ni) {
      const int col = n0 + wn * 64 + ni * 16 + fr;
#pragma unroll
      for (int r = 0; r < 4; ++r) {
        const int row = m0 + wm * 64 + mi * 16 + rq + r;
        float v = acc[mi][ni][r];
        if (LNIN) v = r1[r] * v - rmu[r] * csv[ni] + ctv[ni] + bv[ni];
        else      v = v + bv[ni];
        if (RELU) v = fmaxf(v, 0.0f);
        out[(long)row * N + col] = f2bf(v);
        sv[r] += v; qv[r] += v * v;
      }
    }
#pragma unroll
    for (int r = 0; r < 4; ++r) {
      float s = sv[r], q = qv[r];
#pragma unroll
      for (int off = 1; off < 16; off <<= 1) {
        s += __shfl_xor(s, off);
        q += __shfl_xor(q, off);
      }
      if (fr == 0) {
        const int row = m0 + wm * 64 + mi * 16 + rq + r;
        atomicAdd(&statsOut[row * 2], s);
        atomicAdd(&statsOut[row * 2 + 1], q);
      }
    }
  }
}

// ------- final LN (stats precomputed by gemm3) + transpose to [B][C][N] ------
__global__ __launch_bounds__(256) void ln_tr_out(const short* __restrict__ t3,
                                                 const float* __restrict__ stats,
                                                 const float* __restrict__ g,
                                                 const float* __restrict__ be,
                                                 float* __restrict__ out) {
  __shared__ short tile[64][66];
  const int tx = threadIdx.x;  // 64
  const int ty = threadIdx.y;  // 4
  const int n0 = blockIdx.x * 64;
  const int c0 = blockIdx.y * 64;
  const int b = blockIdx.z;
  const long rbase = ((long)b << 12) + n0;
#pragma unroll
  for (int i = ty; i < 64; i += 4)
    tile[i][tx] = t3[(rbase + i) * 256 + c0 + tx];
  const float s = stats[(rbase + tx) * 2];
  const float q = stats[(rbase + tx) * 2 + 1];
  const float mu = s * (1.0f / 256.0f);
  const float var = fmaxf(q * (1.0f / 256.0f) - mu * mu, 0.0f);
  const float inv = rsqrtf(var + 1e-5f);
  __syncthreads();
  float* ob = out + ((long)b << 20) + n0 + tx;
#pragma unroll
  for (int i = ty; i < 64; i += 4) {
    const int c = c0 + i;
    ob[(long)c * 4096] = (bf2f(tile[tx][i]) - mu) * inv * g[c] + be[c];
  }
}

extern "C" void kernel_launch(void* const* d_in, const int* in_sizes, int n_in,
                              void* d_out, int out_size, void* d_ws, size_t ws_size,
                              hipStream_t stream) {
  (void)n_in; (void)out_size; (void)ws_size;
  const float* x   = (const float*)d_in[0];
  const int*   ei  = (const int*)d_in[1];
  const float* W1  = (const float*)d_in[2];
  const float* b1  = (const float*)d_in[3];
  const float* g1  = (const float*)d_in[4];
  const float* be1 = (const float*)d_in[5];
  const float* W2  = (const float*)d_in[6];
  const float* b2  = (const float*)d_in[7];
  const float* g2  = (const float*)d_in[8];
  const float* be2 = (const float*)d_in[9];
  const float* W3  = (const float*)d_in[10];
  const float* b3  = (const float*)d_in[11];
  const float* go  = (const float*)d_in[12];
  const float* bo  = (const float*)d_in[13];
  float* out = (float*)d_out;
  const int E = in_sizes[1] / 2;  // 65536

  // workspace layout (~75MB)
  char* w = (char*)d_ws;
  int*   deg    = (int*)(w + 0);              // 16K  (zeroed)
  int*   fil    = (int*)(w + (16 << 10));     // 16K  (zeroed)
  float* stats1 = (float*)(w + (32 << 10));   // 128K (zeroed)
  float* stats2 = (float*)(w + (160 << 10));  // 128K (zeroed)
  float* stats3 = (float*)(w + (288 << 10));  // 128K (zeroed)
  float* cs2    = (float*)(w + (416 << 10));  // 2K   (zeroed)
  float* ct2    = (float*)(w + (418 << 10));  // 2K   (zeroed)
  float* cs3    = (float*)(w + (420 << 10));  // 1K   (zeroed)
  float* ct3    = (float*)(w + (421 << 10));  // 1K   (zeroed)
  int*   rp   = (int*)(w + (424 << 10));      // 16.4K
  float* dis  = (float*)(w + (444 << 10));    // 16K
  int*   cols = (int*)(w + (460 << 10));      // 256K
  short* w1t  = (short*)(w + (720 << 10));    // 512K
  short* w2t  = (short*)(w + (1240 << 10));   // 1M
  short* w3t  = (short*)(w + (2264 << 10));   // 256K
  short* xs   = (short*)(w + (3ull << 20));   // 8M  [4096][1024] bf16
  short* h0   = (short*)(w + (11ull << 20));  // 8M  [16384][256]
  short* t1   = (short*)(w + (19ull << 20));  // 32M [16384][1024]
  short* t2   = (short*)(w + (51ull << 20));  // 16M [16384][512]
  short* t3   = (short*)(w + (67ull << 20));  // 8M  [16384][256]

  hipMemsetAsync(d_ws, 0, 422 << 10, stream);
  count_deg<<<256, 256, 0, stream>>>(ei, deg, E);
  scan_deg<<<1, 1024, 0, stream>>>(deg, rp, dis);
  prep<<<5248, dim3(32, 8), 0, stream>>>(ei, rp, fil, cols, E, x, dis, xs,
                                         W1, W2, W3, g1, be1, g2, be2,
                                         w1t, w2t, w3t, cs2, ct2, cs3, ct3);
  gather_mp<<<4096, 256, 0, stream>>>(xs, dis, rp, cols, h0);
  gemm_ln<false, true><<<dim3(128, 8), 256, 0, stream>>>(
      h0, w1t, b1, nullptr, nullptr, nullptr, stats1, t1, 16384, 1024, 256);
  gemm_ln<true, true><<<dim3(128, 4), 256, 0, stream>>>(
      t1, w2t, b2, cs2, ct2, stats1, stats2, t2, 16384, 512, 1024);
  gemm_ln<true, false><<<dim3(128, 2), 256, 0, stream>>>(
      t2, w3t, b3, cs3, ct3, stats2, stats3, t3, 16384, 256, 512);
  ln_tr_out<<<dim3(64, 4, 4), dim3(64, 4), 0, stream>>>(t3, stats3, go, bo, out);
}